// Round 5
// baseline (521.136 us; speedup 1.0000x reference)
//
#include <hip/hip_runtime.h>
#include <hip/hip_bf16.h>
#include <math.h>

typedef __hip_bfloat16 bf16;
typedef __attribute__((ext_vector_type(8))) short bf16x8;   // 8 x bf16 = 4 VGPRs
typedef __attribute__((ext_vector_type(4))) float f32x4;

#define D_MODEL 1024
#define N_HEADS 16
#define HEAD_D  64
#define SEQ     2048
#define BATCH   4
#define NROWS   (BATCH*SEQ)   // 8192

// softmax scale folded into Q at projection time: 1/sqrt(64) * log2(e)
#define SCALE_Q 0.18033688011112042f

#define MFMA(a,b,c) __builtin_amdgcn_mfma_f32_16x16x32_bf16(a,b,c,0,0,0)

#if __has_builtin(__builtin_amdgcn_exp2f)
#define EXP2(x) __builtin_amdgcn_exp2f(x)
#else
#define EXP2(x) exp2f(x)
#endif

// async global->LDS, 16B per lane. LDS dest = wave-uniform base + lane*16.
__device__ __forceinline__ void gload16(void* lds_uniform_base, const void* g) {
  __builtin_amdgcn_global_load_lds(
      (const __attribute__((address_space(1))) void*)g,
      (__attribute__((address_space(3))) void*)lds_uniform_base,
      16, 0, 0);
}

// fast packed f32->bf16 RNE: lo = a, hi = b
__device__ __forceinline__ unsigned pkrne(float a, float b) {
  unsigned ua = __float_as_uint(a), ub = __float_as_uint(b);
  ua += 0x7FFFu + ((ua >> 16) & 1u);
  ub += 0x7FFFu + ((ub >> 16) & 1u);
  return (ua >> 16) | (ub & 0xFFFF0000u);
}
__device__ __forceinline__ bf16x8 cvt8rne(float4 a, float4 b) {
  union { bf16x8 v; unsigned u[4]; } u;
  u.u[0] = pkrne(a.x, a.y); u.u[1] = pkrne(a.z, a.w);
  u.u[2] = pkrne(b.x, b.y); u.u[3] = pkrne(b.z, b.w);
  return u.v;
}

// f32 -> bf16 bulk convert. grid*256*8 == element count.
__global__ __launch_bounds__(256)
void convw(const float* __restrict__ src, bf16* __restrict__ dst) {
  int idx = (blockIdx.x * 256 + threadIdx.x) * 8;
  float4 a = *(const float4*)(src + idx);
  float4 b = *(const float4*)(src + idx + 4);
  *(bf16x8*)(dst + idx) = cvt8rne(a, b);
}

// -------------------------------------------------------------------------
// C(M'xN') = A(M'x1024) @ B(N'x1024)^T + bias, K=1024, all bf16 in.
// MODE 0: out f32 row-major, bias[col]        (O-projection)
// MODE 1: out bf16 K-layout  [((b*16+h)*2048+m)*64+d], bias[col]
// MODE 2: flipped V: row=h*64+d, col=b*2048+m; out[(b*1024+row)*2048+m],
//         bias[row]
// MODE 3: RoPE Q scaled by SCALE_Q, out bf16 [((b*16+h)*2048+t)*64+d]
// block 256 (4 waves), tile 128x128, BK=64.
// LDS: 128 rows x 128B; 16B chunk c of row r stored at chunk c^(r&7).
// -------------------------------------------------------------------------
template<int MODE>
__global__ __launch_bounds__(256, 2)
void gemm_bt(const bf16* __restrict__ Xb, const bf16* __restrict__ Wb,
             const float* __restrict__ bias, void* __restrict__ outv,
             const int* __restrict__ pos) {
  __shared__ bf16 sA[128*64];
  __shared__ bf16 sB[128*64];

  const int tid  = threadIdx.x;
  const int lane = tid & 63, wid = tid >> 6;
  const int q4 = lane >> 4, l15 = lane & 15;
  const int rb = blockIdx.x * 128;
  const int cb = blockIdx.y * 128;
  const int wm = (wid >> 1) * 64, wn = (wid & 1) * 64;

  f32x4 acc[4][4];
  const f32x4 z4 = {0.f, 0.f, 0.f, 0.f};
#pragma unroll
  for (int i = 0; i < 4; ++i)
#pragma unroll
    for (int j = 0; j < 4; ++j) acc[i][j] = z4;

  for (int kt = 0; kt < 16; ++kt) {
    const int k0 = kt * 64;
#pragma unroll
    for (int i = 0; i < 4; ++i) {
      int o  = i*4096 + tid*16;
      int rr = o >> 7;
      int c0 = ((o >> 4) & 7) ^ (rr & 7);
      gload16((char*)sA + i*4096 + (wid << 10),
              Xb + (size_t)(rb + rr)*D_MODEL + k0 + c0*8);
      gload16((char*)sB + i*4096 + (wid << 10),
              Wb + (size_t)(cb + rr)*D_MODEL + k0 + c0*8);
    }
    __syncthreads();
#pragma unroll
    for (int kq = 0; kq < 2; ++kq) {
      bf16x8 af[4], bfr[4];
      const int cc = (kq*4 + q4) ^ (l15 & 7);
#pragma unroll
      for (int mi = 0; mi < 4; ++mi) {
        int r = wm + mi*16 + l15;
        af[mi] = *(const bf16x8*)((const char*)sA + r*128 + cc*16);
      }
#pragma unroll
      for (int ni = 0; ni < 4; ++ni) {
        int r = wn + ni*16 + l15;
        bfr[ni] = *(const bf16x8*)((const char*)sB + r*128 + cc*16);
      }
#pragma unroll
      for (int mi = 0; mi < 4; ++mi)
#pragma unroll
        for (int ni = 0; ni < 4; ++ni)
          acc[mi][ni] = MFMA(af[mi], bfr[ni], acc[mi][ni]);
    }
    __syncthreads();
  }

  // ---------------- epilogue ----------------
  if (MODE == 0) {
    float* outF = (float*)outv;
#pragma unroll
    for (int ni = 0; ni < 4; ++ni) {
      int col = cb + wn + ni*16 + l15;
      float bv = bias[col];
#pragma unroll
      for (int mi = 0; mi < 4; ++mi) {
        int row0 = rb + wm + mi*16 + q4*4;
#pragma unroll
        for (int r = 0; r < 4; ++r)
          outF[(size_t)(row0 + r)*D_MODEL + col] = acc[mi][ni][r] + bv;
      }
    }
  } else if (MODE == 1) {
    bf16* out = (bf16*)outv;
#pragma unroll
    for (int ni = 0; ni < 4; ++ni) {
      int col = cb + wn + ni*16 + l15;
      int h = col >> 6, d = col & 63;
      float bv = bias[col];
#pragma unroll
      for (int mi = 0; mi < 4; ++mi) {
#pragma unroll
        for (int r = 0; r < 4; ++r) {
          int row = rb + wm + mi*16 + q4*4 + r;
          int b = row >> 11, m = row & 2047;
          out[(size_t)((b*N_HEADS + h)*SEQ + m)*HEAD_D + d] =
              __float2bfloat16(acc[mi][ni][r] + bv);
        }
      }
    }
  } else if (MODE == 2) {  // flipped: row = h*64+d, col = b*2048+m
    bf16* out = (bf16*)outv;
#pragma unroll
    for (int mi = 0; mi < 4; ++mi) {
#pragma unroll
      for (int r = 0; r < 4; ++r) {
        int row = rb + wm + mi*16 + q4*4 + r;
        float bv = bias[row];
#pragma unroll
        for (int ni = 0; ni < 4; ++ni) {
          int col = cb + wn + ni*16 + l15;
          int b = col >> 11, m = col & 2047;
          out[(size_t)(b*D_MODEL + row)*SEQ + m] =
              __float2bfloat16(acc[mi][ni][r] + bv);
        }
      }
    }
  } else { // MODE 3: Q with RoPE, scaled by SCALE_Q
    bf16* out = (bf16*)outv;
    const bool is64 = (pos[NROWS - 1] == 0);
    const float CLOG = 13.287712379549449f / 32.0f;  // log2(10000)/32
    float invf0 = exp2f(-(float)(l15)      * CLOG);
    float invf1 = exp2f(-(float)(l15 + 16) * CLOG);
    int h = (cb + wn) >> 6;  // wave covers exactly one head (64 cols)
#pragma unroll
    for (int ni = 0; ni < 2; ++ni) {
      int col1 = cb + wn + ni*16 + l15;
      int d = ni*16 + l15;          // d in [0,32)
      float invf = (ni == 0) ? invf0 : invf1;
      float b1 = bias[col1];
      float b2 = bias[col1 + 32];
#pragma unroll
      for (int mi = 0; mi < 4; ++mi) {
#pragma unroll
        for (int r = 0; r < 4; ++r) {
          int row = rb + wm + mi*16 + q4*4 + r;
          int b = row >> 11, t = row & 2047;
          int pv = is64 ? pos[2*row] : pos[row];
          float ang = (float)pv * invf;
          float sn, cs;
          __sincosf(ang, &sn, &cs);
          float q1 = acc[mi][ni][r]   + b1;
          float q2 = acc[mi][ni+2][r] + b2;
          size_t base = (size_t)((b*N_HEADS + h)*SEQ + t)*HEAD_D;
          out[base + d]      = __float2bfloat16((q1*cs - q2*sn) * SCALE_Q);
          out[base + d + 32] = __float2bfloat16((q2*cs + q1*sn) * SCALE_Q);
        }
      }
    }
  }
}

// -------------------------------------------------------------------------
// Flash attention, S^T formulation + LDS-staged K/VT (round-3 staging with
// round-4 softmax). grid = (T/128, B*H), block 256 (4 waves x 32 q-rows).
// Q[bh][t][d] (pre-scaled), K[bh][m][d], VT[bh][d][m] bf16. O->[b][t][h*64+d].
// LDS (48KB, 3 blocks/CU): sK 16KB @0; sVT 16KB @16K; P regions: waves 0-1
// alias sK (dead after QK), waves 2-3 at [32K,48K). 3 barriers/iter.
// -------------------------------------------------------------------------
__global__ __launch_bounds__(256, 3)
void attn_kernel(const bf16* __restrict__ Q, const bf16* __restrict__ K,
                 const bf16* __restrict__ VT, bf16* __restrict__ O) {
  __shared__ __align__(16) char smem[49152];
  char* sK  = smem;            // 128 rows x 128B, 16B chunks XOR-swizzled
  char* sVT = smem + 16384;    // 64 rows x 256B, 16B chunks XOR-swizzled

  const int tid  = threadIdx.x;
  const int lane = tid & 63, wid = tid >> 6;
  const int q4 = lane >> 4, l15 = lane & 15;
  const int bh = blockIdx.y;
  const int qb = blockIdx.x * 128;

  const bf16* Qp  = Q  + (size_t)bh * SEQ * HEAD_D;
  const bf16* Kp  = K  + (size_t)bh * SEQ * HEAD_D;
  const bf16* VTp = VT + (size_t)bh * HEAD_D * SEQ;
  // per-wave-private P^T: 32 rows(t) x 256B(m), swizzled. 8KB per wave.
  char* wP = smem + (wid & 1) * 8192 + (wid >> 1) * 32768;

  // resident Q fragments (B-operand): lane holds Q[t=l15(+16mi)][k=q4*8+j]
  bf16x8 qf[2][2];
#pragma unroll
  for (int mi = 0; mi < 2; ++mi)
#pragma unroll
    for (int kq = 0; kq < 2; ++kq) {
      int t = qb + wid*32 + mi*16 + l15;
      qf[mi][kq] = *(const bf16x8*)(Qp + (size_t)t*HEAD_D + kq*32 + q4*8);
    }

  const f32x4 z4 = {0.f, 0.f, 0.f, 0.f};
  f32x4 oacc[2][4];                 // O^T tiles: row=d (4q4+r), col=t (l15)
  float mrow[2], lrow[2];           // per-lane; t fixed per lane
#pragma unroll
  for (int mi = 0; mi < 2; ++mi) {
#pragma unroll
    for (int nd = 0; nd < 4; ++nd) oacc[mi][nd] = z4;
    mrow[mi] = -3.0e38f; lrow[mi] = 0.f;
  }

  for (int kv = 0; kv < 16; ++kv) {
    const int m0 = kv * 128;
    // stage K tile (128x64 elems): async, swizzled
#pragma unroll
    for (int i = 0; i < 4; ++i) {
      int o  = i*4096 + tid*16;
      int rr = o >> 7;
      int c0 = ((o >> 4) & 7) ^ (rr & 7);
      gload16(sK + i*4096 + (wid << 10),
              Kp + (size_t)(m0 + rr)*HEAD_D + c0*8);
    }
    // stage VT tile (64x128 elems): async, swizzled
#pragma unroll
    for (int i = 0; i < 4; ++i) {
      int o  = i*4096 + tid*16;
      int rr = o >> 8;
      int c0 = ((o >> 4) & 15) ^ (rr & 7);
      gload16(sVT + i*4096 + (wid << 10),
              VTp + (size_t)rr*SEQ + m0 + c0*8);
    }
    __syncthreads();   // staging complete

    // S^T = K·Q^T : st[mi][ni] row m = ni*16+4q4+r, col t = mi*16+l15
    f32x4 st[2][8];
#pragma unroll
    for (int mi = 0; mi < 2; ++mi)
#pragma unroll
      for (int ni = 0; ni < 8; ++ni) st[mi][ni] = z4;
#pragma unroll
    for (int kq = 0; kq < 2; ++kq) {
      const int cc = (kq*4 + q4) ^ (l15 & 7);
#pragma unroll
      for (int ni = 0; ni < 8; ++ni) {
        bf16x8 kf = *(const bf16x8*)(sK + (ni*16 + l15)*128 + cc*16);
        st[0][ni] = MFMA(kf, qf[0][kq], st[0][ni]);
        st[1][ni] = MFMA(kf, qf[1][kq], st[1][ni]);
      }
    }
    __syncthreads();   // all waves' sK reads done before P aliases it

    // online softmax over m; P^T -> wave-private LDS (no barrier needed)
#pragma unroll
    for (int mi = 0; mi < 2; ++mi) {
      float mloc = st[mi][0][0];
#pragma unroll
      for (int ni = 0; ni < 8; ++ni)
#pragma unroll
        for (int r = 0; r < 4; ++r) mloc = fmaxf(mloc, st[mi][ni][r]);
      mloc = fmaxf(mloc, __shfl_xor(mloc, 16, 64));
      mloc = fmaxf(mloc, __shfl_xor(mloc, 32, 64));
      float mn = fmaxf(mrow[mi], mloc);
      float al = EXP2(mrow[mi] - mn);
      mrow[mi] = mn;
      float rs = 0.f;
#pragma unroll
      for (int ni = 0; ni < 8; ++ni)
#pragma unroll
        for (int r = 0; r < 4; ++r) {
          float p = EXP2(st[mi][ni][r] - mn);
          st[mi][ni][r] = p;
          rs += p;
        }
      lrow[mi] = lrow[mi]*al + rs;
#pragma unroll
      for (int nd = 0; nd < 4; ++nd)
#pragma unroll
        for (int r = 0; r < 4; ++r) oacc[mi][nd][r] *= al;
      // pack 4 consecutive-m p's (in-lane) -> one b64 write per ni
      char* rowp = wP + (mi*16 + l15)*256;
#pragma unroll
      for (int ni = 0; ni < 8; ++ni) {
        uint2 pk;
        pk.x = pkrne(st[mi][ni][0], st[mi][ni][1]);
        pk.y = pkrne(st[mi][ni][2], st[mi][ni][3]);
        int c  = 2*ni + (q4 >> 1);
        int cs = c ^ (l15 & 7);
        *(uint2*)(rowp + cs*16 + 8*(q4 & 1)) = pk;
      }
    }

    // O^T += V^T · P^T  (A = V^T frag from sVT, B = P^T frag from own LDS)
#pragma unroll
    for (int kk = 0; kk < 4; ++kk) {
      const int cc = (kk*4 + q4) ^ (l15 & 7);
      bf16x8 vf[4];
#pragma unroll
      for (int nd = 0; nd < 4; ++nd)
        vf[nd] = *(const bf16x8*)(sVT + (nd*16 + l15)*256 + cc*16);
#pragma unroll
      for (int mi = 0; mi < 2; ++mi) {
        bf16x8 pb = *(const bf16x8*)(wP + (mi*16 + l15)*256 + cc*16);
#pragma unroll
        for (int nd = 0; nd < 4; ++nd)
          oacc[mi][nd] = MFMA(vf[nd], pb, oacc[mi][nd]);
      }
    }
    __syncthreads();   // PV reads done before next-iter staging overwrites
  }

  // epilogue: finish l across quads, O /= l, packed 8B stores
  const int b = bh >> 4, h = bh & 15;
#pragma unroll
  for (int mi = 0; mi < 2; ++mi) {
    float l = lrow[mi];
    l += __shfl_xor(l, 16, 64);
    l += __shfl_xor(l, 32, 64);
    float inv = 1.0f / l;
    int t = qb + wid*32 + mi*16 + l15;
#pragma unroll
    for (int nd = 0; nd < 4; ++nd) {
      uint2 pk;
      pk.x = pkrne(oacc[mi][nd][0]*inv, oacc[mi][nd][1]*inv);
      pk.y = pkrne(oacc[mi][nd][2]*inv, oacc[mi][nd][3]*inv);
      int d = nd*16 + 4*q4;
      *(uint2*)(O + (size_t)(b*SEQ + t)*D_MODEL + h*HEAD_D + d) = pk;
    }
  }
}

// -------------------------------------------------------------------------
extern "C" void kernel_launch(void* const* d_in, const int* in_sizes, int n_in,
                              void* d_out, int out_size, void* d_ws, size_t ws_size,
                              hipStream_t stream) {
  const float* query = (const float*)d_in[0];
  const float* key   = (const float*)d_in[1];
  const float* value = (const float*)d_in[2];
  const int*   pos   = (const int*)d_in[3];
  const float* Wq = (const float*)d_in[4];  const float* bq = (const float*)d_in[5];
  const float* Wk = (const float*)d_in[6];  const float* bk = (const float*)d_in[7];
  const float* Wv = (const float*)d_in[8];  const float* bv = (const float*)d_in[9];
  const float* Wo = (const float*)d_in[10]; const float* bo = (const float*)d_in[11];

  // ws layout (64 MB):
  //  [0,16M)  qbuf bf16 [b,h,t,d];  after attn: first 2MB = Wo bf16
  //  [16,32M) kbuf bf16 [b,h,m,d]
  //  [32,48M) vtbuf bf16 [b,h,d,m]
  //  [48,64M) obuf bf16 [b,t,h*64+d]; before attn: first 6MB = Wq/Wk/Wv bf16
  // d_out (32MB f32) doubles as bf16 activation scratch (16MB) until O-GEMM.
  char* ws = (char*)d_ws;
  bf16* qbuf  = (bf16*)(ws);
  bf16* kbuf  = (bf16*)(ws + (size_t)16777216);
  bf16* vtbuf = (bf16*)(ws + (size_t)33554432);
  bf16* obuf  = (bf16*)(ws + (size_t)50331648);
  bf16* wqb = obuf;                       // 1M bf16 = 2MB each
  bf16* wkb = obuf + (size_t)1048576;
  bf16* wvb = obuf + (size_t)2097152;
  bf16* wob = qbuf;                       // written AFTER attn consumes qbuf
  bf16* xact = (bf16*)d_out;              // activation scratch in d_out

  dim3 blk(256);
  dim3 gproj(NROWS/128, D_MODEL/128);     // 64 x 8
  dim3 gprojT(D_MODEL/128, NROWS/128);    // 8 x 64 (flipped V)

  // weights -> bf16 (2MB each)
  convw<<<512, blk, 0, stream>>>(Wq, wqb);
  convw<<<512, blk, 0, stream>>>(Wk, wkb);
  convw<<<512, blk, 0, stream>>>(Wv, wvb);

  // V^T = (Wv X^T): A=wv bf16, B=value bf16 (converted into d_out scratch)
  convw<<<4096, blk, 0, stream>>>(value, xact);
  gemm_bt<2><<<gprojT, blk, 0, stream>>>(wvb, xact, bv, vtbuf, nullptr);

  convw<<<4096, blk, 0, stream>>>(key, xact);
  gemm_bt<1><<<gproj,  blk, 0, stream>>>(xact, wkb, bk, kbuf, nullptr);

  convw<<<4096, blk, 0, stream>>>(query, xact);
  gemm_bt<3><<<gproj,  blk, 0, stream>>>(xact, wqb, bq, qbuf, pos);

  attn_kernel<<<dim3(SEQ/128, BATCH*N_HEADS), blk, 0, stream>>>(qbuf, kbuf, vtbuf, obuf);

  // O-projection: A=obuf bf16, B=Wo bf16 (into qbuf, dead after attn), f32 out
  convw<<<512, blk, 0, stream>>>(Wo, wob);
  gemm_bt<0><<<gproj,  blk, 0, stream>>>(obuf, wob, bo, d_out, nullptr);
  (void)in_sizes; (void)n_in; (void)out_size; (void)ws_size;
}

// Round 6
// 384.557 us; speedup vs baseline: 1.3552x; 1.3552x over previous
//
#include <hip/hip_runtime.h>
#include <hip/hip_bf16.h>
#include <math.h>

typedef __hip_bfloat16 bf16;
typedef __attribute__((ext_vector_type(8))) short bf16x8;   // 8 x bf16 = 4 VGPRs
typedef __attribute__((ext_vector_type(4))) float f32x4;

#define D_MODEL 1024
#define N_HEADS 16
#define HEAD_D  64
#define SEQ     2048
#define BATCH   4
#define NROWS   (BATCH*SEQ)   // 8192

// softmax scale folded into Q at projection time: 1/sqrt(64) * log2(e)
#define SCALE_Q 0.18033688011112042f

#define MFMA(a,b,c) __builtin_amdgcn_mfma_f32_16x16x32_bf16(a,b,c,0,0,0)

#if __has_builtin(__builtin_amdgcn_exp2f)
#define EXP2(x) __builtin_amdgcn_exp2f(x)
#else
#define EXP2(x) exp2f(x)
#endif

// async global->LDS, 16B per lane. LDS dest = wave-uniform base + lane*16.
__device__ __forceinline__ void gload16(void* lds_uniform_base, const void* g) {
  __builtin_amdgcn_global_load_lds(
      (const __attribute__((address_space(1))) void*)g,
      (__attribute__((address_space(3))) void*)lds_uniform_base,
      16, 0, 0);
}

// fast packed f32->bf16 RNE: lo = a, hi = b
__device__ __forceinline__ unsigned pkrne(float a, float b) {
  unsigned ua = __float_as_uint(a), ub = __float_as_uint(b);
  ua += 0x7FFFu + ((ua >> 16) & 1u);
  ub += 0x7FFFu + ((ub >> 16) & 1u);
  return (ua >> 16) | (ub & 0xFFFF0000u);
}
__device__ __forceinline__ bf16x8 cvt8rne(float4 a, float4 b) {
  union { bf16x8 v; unsigned u[4]; } u;
  u.u[0] = pkrne(a.x, a.y); u.u[1] = pkrne(a.z, a.w);
  u.u[2] = pkrne(b.x, b.y); u.u[3] = pkrne(b.z, b.w);
  return u.v;
}

// f32 -> bf16 bulk convert. grid*256*8 == element count.
__global__ __launch_bounds__(256)
void convw(const float* __restrict__ src, bf16* __restrict__ dst) {
  int idx = (blockIdx.x * 256 + threadIdx.x) * 8;
  float4 a = *(const float4*)(src + idx);
  float4 b = *(const float4*)(src + idx + 4);
  *(bf16x8*)(dst + idx) = cvt8rne(a, b);
}

// -------------------------------------------------------------------------
// C(M'xN') = A(M'x1024) @ B(N'x1024)^T + bias, K=1024, all bf16 in.
// MODE 0: out f32 row-major, bias[col]        (O-projection)
// MODE 1: out bf16 K-layout  [((b*16+h)*2048+m)*64+d], bias[col]
// MODE 2: flipped V: row=h*64+d, col=b*2048+m; out[(b*1024+row)*2048+m],
//         bias[row]
// MODE 3: RoPE Q scaled by SCALE_Q, out bf16 [((b*16+h)*2048+t)*64+d]
// block 256 (4 waves), tile 128x128, BK=64.
// LDS: 128 rows x 128B; 16B chunk c of row r stored at chunk c^(r&7).
// -------------------------------------------------------------------------
template<int MODE>
__global__ __launch_bounds__(256, 2)
void gemm_bt(const bf16* __restrict__ Xb, const bf16* __restrict__ Wb,
             const float* __restrict__ bias, void* __restrict__ outv,
             const int* __restrict__ pos) {
  __shared__ bf16 sA[128*64];
  __shared__ bf16 sB[128*64];

  const int tid  = threadIdx.x;
  const int lane = tid & 63, wid = tid >> 6;
  const int q4 = lane >> 4, l15 = lane & 15;
  const int rb = blockIdx.x * 128;
  const int cb = blockIdx.y * 128;
  const int wm = (wid >> 1) * 64, wn = (wid & 1) * 64;

  f32x4 acc[4][4];
  const f32x4 z4 = {0.f, 0.f, 0.f, 0.f};
#pragma unroll
  for (int i = 0; i < 4; ++i)
#pragma unroll
    for (int j = 0; j < 4; ++j) acc[i][j] = z4;

  for (int kt = 0; kt < 16; ++kt) {
    const int k0 = kt * 64;
#pragma unroll
    for (int i = 0; i < 4; ++i) {
      int o  = i*4096 + tid*16;
      int rr = o >> 7;
      int c0 = ((o >> 4) & 7) ^ (rr & 7);
      gload16((char*)sA + i*4096 + (wid << 10),
              Xb + (size_t)(rb + rr)*D_MODEL + k0 + c0*8);
      gload16((char*)sB + i*4096 + (wid << 10),
              Wb + (size_t)(cb + rr)*D_MODEL + k0 + c0*8);
    }
    __syncthreads();
#pragma unroll
    for (int kq = 0; kq < 2; ++kq) {
      bf16x8 af[4], bfr[4];
      const int cc = (kq*4 + q4) ^ (l15 & 7);
#pragma unroll
      for (int mi = 0; mi < 4; ++mi) {
        int r = wm + mi*16 + l15;
        af[mi] = *(const bf16x8*)((const char*)sA + r*128 + cc*16);
      }
#pragma unroll
      for (int ni = 0; ni < 4; ++ni) {
        int r = wn + ni*16 + l15;
        bfr[ni] = *(const bf16x8*)((const char*)sB + r*128 + cc*16);
      }
#pragma unroll
      for (int mi = 0; mi < 4; ++mi)
#pragma unroll
        for (int ni = 0; ni < 4; ++ni)
          acc[mi][ni] = MFMA(af[mi], bfr[ni], acc[mi][ni]);
    }
    __syncthreads();
  }

  // ---------------- epilogue ----------------
  if (MODE == 0) {
    float* outF = (float*)outv;
#pragma unroll
    for (int ni = 0; ni < 4; ++ni) {
      int col = cb + wn + ni*16 + l15;
      float bv = bias[col];
#pragma unroll
      for (int mi = 0; mi < 4; ++mi) {
        int row0 = rb + wm + mi*16 + q4*4;
#pragma unroll
        for (int r = 0; r < 4; ++r)
          outF[(size_t)(row0 + r)*D_MODEL + col] = acc[mi][ni][r] + bv;
      }
    }
  } else if (MODE == 1) {
    bf16* out = (bf16*)outv;
#pragma unroll
    for (int ni = 0; ni < 4; ++ni) {
      int col = cb + wn + ni*16 + l15;
      int h = col >> 6, d = col & 63;
      float bv = bias[col];
#pragma unroll
      for (int mi = 0; mi < 4; ++mi) {
#pragma unroll
        for (int r = 0; r < 4; ++r) {
          int row = rb + wm + mi*16 + q4*4 + r;
          int b = row >> 11, m = row & 2047;
          out[(size_t)((b*N_HEADS + h)*SEQ + m)*HEAD_D + d] =
              __float2bfloat16(acc[mi][ni][r] + bv);
        }
      }
    }
  } else if (MODE == 2) {  // flipped: row = h*64+d, col = b*2048+m
    bf16* out = (bf16*)outv;
#pragma unroll
    for (int mi = 0; mi < 4; ++mi) {
#pragma unroll
      for (int r = 0; r < 4; ++r) {
        int row = rb + wm + mi*16 + q4*4 + r;
        float bv = bias[row];
#pragma unroll
        for (int ni = 0; ni < 4; ++ni) {
          int col = cb + wn + ni*16 + l15;
          int b = col >> 11, m = col & 2047;
          out[(size_t)(b*D_MODEL + row)*SEQ + m] =
              __float2bfloat16(acc[mi][ni][r] + bv);
        }
      }
    }
  } else { // MODE 3: Q with RoPE, scaled by SCALE_Q
    bf16* out = (bf16*)outv;
    const bool is64 = (pos[NROWS - 1] == 0);
    const float CLOG = 13.287712379549449f / 32.0f;  // log2(10000)/32
    float invf0 = exp2f(-(float)(l15)      * CLOG);
    float invf1 = exp2f(-(float)(l15 + 16) * CLOG);
    int h = (cb + wn) >> 6;  // wave covers exactly one head (64 cols)
#pragma unroll
    for (int ni = 0; ni < 2; ++ni) {
      int col1 = cb + wn + ni*16 + l15;
      int d = ni*16 + l15;          // d in [0,32)
      float invf = (ni == 0) ? invf0 : invf1;
      float b1 = bias[col1];
      float b2 = bias[col1 + 32];
#pragma unroll
      for (int mi = 0; mi < 4; ++mi) {
#pragma unroll
        for (int r = 0; r < 4; ++r) {
          int row = rb + wm + mi*16 + q4*4 + r;
          int b = row >> 11, t = row & 2047;
          int pv = is64 ? pos[2*row] : pos[row];
          float ang = (float)pv * invf;
          float sn, cs;
          __sincosf(ang, &sn, &cs);
          float q1 = acc[mi][ni][r]   + b1;
          float q2 = acc[mi][ni+2][r] + b2;
          size_t base = (size_t)((b*N_HEADS + h)*SEQ + t)*HEAD_D;
          out[base + d]      = __float2bfloat16((q1*cs - q2*sn) * SCALE_Q);
          out[base + d + 32] = __float2bfloat16((q2*cs + q1*sn) * SCALE_Q);
        }
      }
    }
  }
}

// -------------------------------------------------------------------------
// Flash attention, S^T formulation + LDS-staged K/VT.
// grid = 1024 blocks 1D, XCD-swizzled: linear id n -> xcd-slot c=n&7,
// qt=(n>>3)&15, bh=c+8*(n>>7): all 16 q-tiles of one bh share n%8 -> same
// XCD L2 caches that bh's K/VT strips.
// block 256 (4 waves x 32 q-rows). Q pre-scaled by SCALE_Q (base-2 softmax).
// LDS (48KB): sK 16KB @0; sVT 16KB @16K; P: waves 0-1 alias sK (dead after
// QK barrier), waves 2-3 at [32K,48K). 3 barriers/iter.
// __launch_bounds__(256,2): round-5's (256,3) capped regs at ~170 and
// spilled ~500MB/dispatch to scratch (WRITE_SIZE 16->271MB). Keep 2.
// -------------------------------------------------------------------------
__global__ __launch_bounds__(256, 2)
void attn_kernel(const bf16* __restrict__ Q, const bf16* __restrict__ K,
                 const bf16* __restrict__ VT, bf16* __restrict__ O) {
  __shared__ __align__(16) char smem[49152];
  char* sK  = smem;            // 128 rows x 128B, 16B chunks XOR-swizzled
  char* sVT = smem + 16384;    // 64 rows x 256B, 16B chunks XOR-swizzled

  const int tid  = threadIdx.x;
  const int lane = tid & 63, wid = tid >> 6;
  const int q4 = lane >> 4, l15 = lane & 15;
  const int n   = blockIdx.x;
  const int bh  = (n & 7) + 8 * (n >> 7);
  const int qb  = ((n >> 3) & 15) * 128;

  const bf16* Qp  = Q  + (size_t)bh * SEQ * HEAD_D;
  const bf16* Kp  = K  + (size_t)bh * SEQ * HEAD_D;
  const bf16* VTp = VT + (size_t)bh * HEAD_D * SEQ;
  // per-wave-private P^T: 32 rows(t) x 256B(m), swizzled. 8KB per wave.
  char* wP = smem + (wid & 1) * 8192 + (wid >> 1) * 32768;

  // resident Q fragments (B-operand): lane holds Q[t=l15(+16mi)][k=q4*8+j]
  bf16x8 qf[2][2];
#pragma unroll
  for (int mi = 0; mi < 2; ++mi)
#pragma unroll
    for (int kq = 0; kq < 2; ++kq) {
      int t = qb + wid*32 + mi*16 + l15;
      qf[mi][kq] = *(const bf16x8*)(Qp + (size_t)t*HEAD_D + kq*32 + q4*8);
    }

  const f32x4 z4 = {0.f, 0.f, 0.f, 0.f};
  f32x4 oacc[2][4];                 // O^T tiles: row=d (4q4+r), col=t (l15)
  float mrow[2], lrow[2];           // per-lane; t fixed per lane
#pragma unroll
  for (int mi = 0; mi < 2; ++mi) {
#pragma unroll
    for (int nd = 0; nd < 4; ++nd) oacc[mi][nd] = z4;
    mrow[mi] = -3.0e38f; lrow[mi] = 0.f;
  }

  for (int kv = 0; kv < 16; ++kv) {
    const int m0 = kv * 128;
    // stage K tile (128x64 elems): async, swizzled
#pragma unroll
    for (int i = 0; i < 4; ++i) {
      int o  = i*4096 + tid*16;
      int rr = o >> 7;
      int c0 = ((o >> 4) & 7) ^ (rr & 7);
      gload16(sK + i*4096 + (wid << 10),
              Kp + (size_t)(m0 + rr)*HEAD_D + c0*8);
    }
    // stage VT tile (64x128 elems): async, swizzled
#pragma unroll
    for (int i = 0; i < 4; ++i) {
      int o  = i*4096 + tid*16;
      int rr = o >> 8;
      int c0 = ((o >> 4) & 15) ^ (rr & 7);
      gload16(sVT + i*4096 + (wid << 10),
              VTp + (size_t)rr*SEQ + m0 + c0*8);
    }
    __syncthreads();   // staging complete

    // S^T = K·Q^T : st[mi][ni] row m = ni*16+4q4+r, col t = mi*16+l15
    f32x4 st[2][8];
#pragma unroll
    for (int mi = 0; mi < 2; ++mi)
#pragma unroll
      for (int ni = 0; ni < 8; ++ni) st[mi][ni] = z4;
#pragma unroll
    for (int kq = 0; kq < 2; ++kq) {
      const int cc = (kq*4 + q4) ^ (l15 & 7);
#pragma unroll
      for (int ni = 0; ni < 8; ++ni) {
        bf16x8 kf = *(const bf16x8*)(sK + (ni*16 + l15)*128 + cc*16);
        st[0][ni] = MFMA(kf, qf[0][kq], st[0][ni]);
        st[1][ni] = MFMA(kf, qf[1][kq], st[1][ni]);
      }
    }
    __syncthreads();   // all waves' sK reads done before P aliases it

    // online softmax over m; P^T -> wave-private LDS (no barrier needed)
#pragma unroll
    for (int mi = 0; mi < 2; ++mi) {
      float mloc = st[mi][0][0];
#pragma unroll
      for (int ni = 0; ni < 8; ++ni)
#pragma unroll
        for (int r = 0; r < 4; ++r) mloc = fmaxf(mloc, st[mi][ni][r]);
      mloc = fmaxf(mloc, __shfl_xor(mloc, 16, 64));
      mloc = fmaxf(mloc, __shfl_xor(mloc, 32, 64));
      float mn = fmaxf(mrow[mi], mloc);
      float al = EXP2(mrow[mi] - mn);
      mrow[mi] = mn;
      float rs = 0.f;
#pragma unroll
      for (int ni = 0; ni < 8; ++ni)
#pragma unroll
        for (int r = 0; r < 4; ++r) {
          float p = EXP2(st[mi][ni][r] - mn);
          st[mi][ni][r] = p;
          rs += p;
        }
      lrow[mi] = lrow[mi]*al + rs;
#pragma unroll
      for (int nd = 0; nd < 4; ++nd)
#pragma unroll
        for (int r = 0; r < 4; ++r) oacc[mi][nd][r] *= al;
      // pack 4 consecutive-m p's (in-lane) -> one b64 write per ni
      char* rowp = wP + (mi*16 + l15)*256;
#pragma unroll
      for (int ni = 0; ni < 8; ++ni) {
        uint2 pk;
        pk.x = pkrne(st[mi][ni][0], st[mi][ni][1]);
        pk.y = pkrne(st[mi][ni][2], st[mi][ni][3]);
        int c  = 2*ni + (q4 >> 1);
        int cs = c ^ (l15 & 7);
        *(uint2*)(rowp + cs*16 + 8*(q4 & 1)) = pk;
      }
    }

    // O^T += V^T · P^T  (A = V^T frag from sVT, B = P^T frag from own LDS)
#pragma unroll
    for (int kk = 0; kk < 4; ++kk) {
      const int cc = (kk*4 + q4) ^ (l15 & 7);
      bf16x8 vf[4];
#pragma unroll
      for (int nd = 0; nd < 4; ++nd)
        vf[nd] = *(const bf16x8*)(sVT + (nd*16 + l15)*256 + cc*16);
#pragma unroll
      for (int mi = 0; mi < 2; ++mi) {
        bf16x8 pb = *(const bf16x8*)(wP + (mi*16 + l15)*256 + cc*16);
#pragma unroll
        for (int nd = 0; nd < 4; ++nd)
          oacc[mi][nd] = MFMA(vf[nd], pb, oacc[mi][nd]);
      }
    }
    __syncthreads();   // PV reads done before next-iter staging overwrites
  }

  // epilogue: finish l across quads, O /= l, packed 8B stores
  const int b = bh >> 4, h = bh & 15;
#pragma unroll
  for (int mi = 0; mi < 2; ++mi) {
    float l = lrow[mi];
    l += __shfl_xor(l, 16, 64);
    l += __shfl_xor(l, 32, 64);
    float inv = 1.0f / l;
    int t = qb + wid*32 + mi*16 + l15;
#pragma unroll
    for (int nd = 0; nd < 4; ++nd) {
      uint2 pk;
      pk.x = pkrne(oacc[mi][nd][0]*inv, oacc[mi][nd][1]*inv);
      pk.y = pkrne(oacc[mi][nd][2]*inv, oacc[mi][nd][3]*inv);
      int d = nd*16 + 4*q4;
      *(uint2*)(O + (size_t)(b*SEQ + t)*D_MODEL + h*HEAD_D + d) = pk;
    }
  }
}

// -------------------------------------------------------------------------
extern "C" void kernel_launch(void* const* d_in, const int* in_sizes, int n_in,
                              void* d_out, int out_size, void* d_ws, size_t ws_size,
                              hipStream_t stream) {
  const float* query = (const float*)d_in[0];
  const float* key   = (const float*)d_in[1];
  const float* value = (const float*)d_in[2];
  const int*   pos   = (const int*)d_in[3];
  const float* Wq = (const float*)d_in[4];  const float* bq = (const float*)d_in[5];
  const float* Wk = (const float*)d_in[6];  const float* bk = (const float*)d_in[7];
  const float* Wv = (const float*)d_in[8];  const float* bv = (const float*)d_in[9];
  const float* Wo = (const float*)d_in[10]; const float* bo = (const float*)d_in[11];

  // ws layout (64 MB):
  //  [0,16M)  qbuf bf16 [b,h,t,d];  after attn: first 2MB = Wo bf16
  //  [16,32M) kbuf bf16 [b,h,m,d]
  //  [32,48M) vtbuf bf16 [b,h,d,m]
  //  [48,64M) obuf bf16 [b,t,h*64+d]; before attn: first 6MB = Wq/Wk/Wv bf16
  // d_out (32MB f32) doubles as bf16 activation scratch (16MB) until O-GEMM.
  char* ws = (char*)d_ws;
  bf16* qbuf  = (bf16*)(ws);
  bf16* kbuf  = (bf16*)(ws + (size_t)16777216);
  bf16* vtbuf = (bf16*)(ws + (size_t)33554432);
  bf16* obuf  = (bf16*)(ws + (size_t)50331648);
  bf16* wqb = obuf;                       // 1M bf16 = 2MB each
  bf16* wkb = obuf + (size_t)1048576;
  bf16* wvb = obuf + (size_t)2097152;
  bf16* wob = qbuf;                       // written AFTER attn consumes qbuf
  bf16* xact = (bf16*)d_out;              // activation scratch in d_out

  dim3 blk(256);
  dim3 gproj(NROWS/128, D_MODEL/128);     // 64 x 8
  dim3 gprojT(D_MODEL/128, NROWS/128);    // 8 x 64 (flipped V)

  // weights -> bf16 (2MB each)
  convw<<<512, blk, 0, stream>>>(Wq, wqb);
  convw<<<512, blk, 0, stream>>>(Wk, wkb);
  convw<<<512, blk, 0, stream>>>(Wv, wvb);

  // V^T = (Wv X^T): A=wv bf16, B=value bf16 (converted into d_out scratch)
  convw<<<4096, blk, 0, stream>>>(value, xact);
  gemm_bt<2><<<gprojT, blk, 0, stream>>>(wvb, xact, bv, vtbuf, nullptr);

  convw<<<4096, blk, 0, stream>>>(key, xact);
  gemm_bt<1><<<gproj,  blk, 0, stream>>>(xact, wkb, bk, kbuf, nullptr);

  convw<<<4096, blk, 0, stream>>>(query, xact);
  gemm_bt<3><<<gproj,  blk, 0, stream>>>(xact, wqb, bq, qbuf, pos);

  attn_kernel<<<dim3(1024), blk, 0, stream>>>(qbuf, kbuf, vtbuf, obuf);

  // O-projection: A=obuf bf16, B=Wo bf16 (into qbuf, dead after attn), f32 out
  convw<<<512, blk, 0, stream>>>(Wo, wob);
  gemm_bt<0><<<gproj,  blk, 0, stream>>>(obuf, wob, bo, d_out, nullptr);
  (void)in_sizes; (void)n_in; (void)out_size; (void)ws_size;
}